// Round 7
// baseline (891.486 us; speedup 1.0000x reference)
//
#include <hip/hip_runtime.h>
#include <stdint.h>

// Problem constants (fixed by setup_inputs): B=16, N=2048, D=768
#define BB 16
#define NN 2048
#define DD 768
#define BN (BB*NN)          // 32768 rows per tensor

// ---------------------------------------------------------------------------
// Memory plan:
//  ws (floats):
//   [0,     65536)  pmax  [b][ms(2)][n]
//   [65536,131072)  pidx  (int)                        -> 0.5 MB total
//  d_out doubles as scratch: out_ri region holds qh|ql (bf16 hi/lo of
//  normalized query_input), out_rv region holds ch|cl — both are dead
//  until blend_kernel overwrites them at the very end.
//
// bf16x3 trick: x = hi + lo (both bf16, RNE). dot(nq,nc) = hh + lh + hl
// (+ ll dropped, |err| <= sum|a*b| * 2^-18 ~ 5e-6 on a cosine score).
//
// ROUND-7 CHANGES:
//  * simmax rebuilt as 256x256-tile 4-phase pipelined kernel (8 waves,
//    BK=32, 2 LDS buffers, 128KB). Staging gloads issued at phases 0-1,
//    single vmcnt(0) at phase 3 (~500cy after last issue -> loads span
//    barriers, m218 counted-vmcnt effect), 96 MFMA per drain (2x the old
//    amortization), setprio around MFMA clusters (T5, structure-
//    conditional). Running max/argmax folded into LDS per m-tile so acc
//    (128 VGPR) doesn't coexist with running state.
//  * msplit 4 -> 2 (grid 8x2x16 = 256 blocks = 1/CU).
// ---------------------------------------------------------------------------

typedef __attribute__((ext_vector_type(8))) short bf16x8;   // 4 VGPRs
typedef __attribute__((ext_vector_type(4))) float f32x4;    // 4 VGPRs

__device__ __forceinline__ ushort f2bf_rne(float x) {
    uint32_t u = __float_as_uint(x);
    u += 0x7fffu + ((u >> 16) & 1u);
    return (ushort)(u >> 16);
}

__device__ __forceinline__ void gload16(const void* g, void* l) {
    __builtin_amdgcn_global_load_lds(
        (const __attribute__((address_space(1))) void*)g,
        (__attribute__((address_space(3))) void*)l,
        16, 0, 0);
}

// --- Kernel 1: per-row L2 norm + normalized bf16 hi/lo split ---------------
__global__ __launch_bounds__(256) void normconv_kernel(
        const float* __restrict__ qi, const float* __restrict__ ci,
        ushort* __restrict__ qh, ushort* __restrict__ ql,
        ushort* __restrict__ ch, ushort* __restrict__ cl) {
    const int gw   = blockIdx.x * 4 + (threadIdx.x >> 6);   // [0, 8192)
    const int lane = threadIdx.x & 63;
#pragma unroll
    for (int it = 0; it < 8; it++) {
        int row = gw + it * 8192;
        bool isq = row < BN;
        const float* src = isq ? qi : ci;
        int r = row & (BN - 1);
        const float4* p = (const float4*)(src + (size_t)r * DD);
        float4 v[3];
        float s = 0.0f;
#pragma unroll
        for (int k = 0; k < 3; k++) {
            v[k] = p[lane + 64 * k];
            s += v[k].x*v[k].x + v[k].y*v[k].y + v[k].z*v[k].z + v[k].w*v[k].w;
        }
#pragma unroll
        for (int off = 32; off; off >>= 1) s += __shfl_xor(s, off);
        float inv = 1.0f / sqrtf(s);
        ushort* dh = (isq ? qh : ch) + (size_t)r * DD;
        ushort* dl = (isq ? ql : cl) + (size_t)r * DD;
#pragma unroll
        for (int k = 0; k < 3; k++) {
            int f = lane + 64 * k;
            float n[4] = {v[k].x * inv, v[k].y * inv, v[k].z * inv, v[k].w * inv};
            ushort hs[4], ls[4];
#pragma unroll
            for (int e = 0; e < 4; e++) {
                hs[e] = f2bf_rne(n[e]);
                ls[e] = f2bf_rne(n[e] - __uint_as_float((uint32_t)hs[e] << 16));
            }
            uint2 hv, lv;
            hv.x = (uint32_t)hs[0] | ((uint32_t)hs[1] << 16);
            hv.y = (uint32_t)hs[2] | ((uint32_t)hs[3] << 16);
            lv.x = (uint32_t)ls[0] | ((uint32_t)ls[1] << 16);
            lv.y = (uint32_t)ls[2] | ((uint32_t)ls[3] << 16);
            *(uint2*)(dh + 4 * (size_t)f) = hv;
            *(uint2*)(dl + 4 * (size_t)f) = lv;
        }
    }
}

// --- Kernel 2: 256x256 4-phase MFMA GEMM (bf16x3) + max/argmax -------------
// grid (8 n-tiles, 2 msplit, 16 b) = 256 blocks = 1/CU. 8 waves as 2x4:
// wave (wy,wx) owns rows wy*128+[0,128) x cols wx*64+[0,64).
// Frags 16x16x32: A row = wy*128+iq*64+i*16+fr, k=fs*8; B row(m) =
// wx*64+(jh*2+j)*16+fr; D: col=fr (m), row=i*16+fs*4+r (n). [m89/m92]
// LDS: sA/sB [2buf][hi,lo][256r][4 slots x 8]; phys slot = logical ^
// ((row>>1)&3); staged via pre-swizzled global srcs, lane-linear dest.
// Per K-tile (BK=32): P0{issue uA0,uB0; read A(iq0)+B(jh0); 24 MFMA; bar}
// P1{issue uA1,uB1; read B(jh1); MFMA(iq0,jh1); bar} P2{read A(iq1);
// MFMA(iq1,jh1); bar} P3{read B(jh0); MFMA(iq1,jh0); vmcnt(0); bar}.
// vmcnt(0) is >=2 phases after last issue -> loads span barriers (T3/T4).
__global__ __launch_bounds__(512, 2) void simmax_kernel(
        const ushort* __restrict__ qh, const ushort* __restrict__ ql,
        const ushort* __restrict__ ch, const ushort* __restrict__ cl,
        float* __restrict__ pmax, int* __restrict__ pidx) {
    __shared__ ushort sA[2][2][256 * 32];     // 64 KiB
    __shared__ ushort sB[2][2][256 * 32];     // 64 KiB
    __shared__ float  redm[4][256];           // running max per wx
    __shared__ int    redi[4][256];

    const int t   = threadIdx.x;              // [0,512)
    const int l   = t & 63, wid = t >> 6;     // wave [0,8)
    const int wy  = wid >> 2, wx = wid & 3;
    const int fr  = l & 15,  fs = l >> 4;
    const int n0  = blockIdx.x * 256;
    const int ms  = blockIdx.y;               // msplit in {0,1}
    const int b   = blockIdx.z;
    const int n0g = b * NN + n0;

    // staging lane map: wave wid stages rows [wid*16, wid*16+16) of a
    // 128-row half; lane l -> row + (l>>2), LDS phys slot l&3, global
    // slot gs = (l&3)^((l>>3)&3)  (== (l&3)^((row>>1)&3))
    const int rowl = l >> 2;
    const int gs   = (l & 3) ^ ((l >> 3) & 3);
    const int wr16 = wid * 16;                // wave's stage-row base in half

    // fragment read bases: phys slot = fs ^ ((fr>>1)&3)
    const int psl = (fs ^ ((fr >> 1) & 3)) * 8;
    const int rA  = (wy * 128 + fr) * 32 + psl;   // + iq*2048 + i*512
    const int rB  = (wx * 64 + fr) * 32 + psl;    // + j*512

    // init running max
    for (int u = t; u < 1024; u += 512) {
        ((float*)redm)[u] = -3.0e38f;
        ((int*)redi)[u]   = 0;
    }

// stage one 128-row half of one hi/lo pair for K-chunk at ko (elems)
#define STG(srcH, srcL, dH, dL, growbase, ko)                                \
    {                                                                        \
        const size_t off_ = (size_t)((growbase) + rowl) * DD + (ko) + gs * 8;\
        gload16((srcH) + off_, (dH));                                        \
        gload16((srcL) + off_, (dL));                                        \
    }
#define STG_A(nb, ih, ko) STG(qh, ql,                                        \
        &sA[nb][0][((ih)*128 + wr16) * 32], &sA[nb][1][((ih)*128 + wr16)*32],\
        n0g + (ih)*128 + wr16, ko)
#define STG_B(nb, mh, m0gn, ko) STG(ch, cl,                                  \
        &sB[nb][0][((mh)*128 + wr16) * 32], &sB[nb][1][((mh)*128 + wr16)*32],\
        (m0gn) + (mh)*128 + wr16, ko)

    // prologue: stage m-tile ms, K-tile 0 into buf 0
    {
        const int m0gn = b * NN + ms * 256;
        STG_A(0, 0, 0); STG_B(0, 0, m0gn, 0);
        STG_A(0, 1, 0); STG_B(0, 1, m0gn, 0);
    }
    asm volatile("s_waitcnt vmcnt(0)" ::: "memory");
    __builtin_amdgcn_s_barrier();
    __builtin_amdgcn_sched_barrier(0);

    int cur = 0;
#pragma unroll 1
    for (int q = 0; q < 4; q++) {             // m-tiles ms, ms+2, ms+4, ms+6
        const int mt  = ms + 2 * q;
        const int m0  = mt * 256;
        const int m0g = b * NN + m0;

        f32x4 acc[8][4];
#pragma unroll
        for (int i = 0; i < 8; i++)
#pragma unroll
            for (int j = 0; j < 4; j++)
#pragma unroll
                for (int r = 0; r < 4; r++) acc[i][j][r] = 0.0f;

        bf16x8 aH[4], aL[4];

#pragma unroll 1
        for (int kt = 0; kt < 24; kt++) {
            const bool hasNext = !(q == 3 && kt == 23);
            const int  kn      = (kt < 23) ? (kt + 1) * 32 : 0;
            const int  m0gn    = (kt < 23) ? m0g : b * NN + (mt + 2) * 256;
            const int  nb      = cur ^ 1;
            bf16x8 bH[2], bL[2];

            // ---- P0: quadrant (iq0, jh0); issue next uA0+uB0 ----
            if (hasNext) { STG_A(nb, 0, kn); STG_B(nb, 0, m0gn, kn); }
#pragma unroll
            for (int i = 0; i < 4; i++) {
                aH[i] = *(const bf16x8*)&sA[cur][0][rA + i * 512];
                aL[i] = *(const bf16x8*)&sA[cur][1][rA + i * 512];
            }
#pragma unroll
            for (int j = 0; j < 2; j++) {
                bH[j] = *(const bf16x8*)&sB[cur][0][rB + j * 512];
                bL[j] = *(const bf16x8*)&sB[cur][1][rB + j * 512];
            }
            __builtin_amdgcn_s_setprio(1);
#pragma unroll
            for (int i = 0; i < 4; i++)
#pragma unroll
                for (int j = 0; j < 2; j++) {
                    asm("v_mfma_f32_16x16x32_bf16 %0, %1, %2, %0"
                        : "+v"(acc[i][j]) : "v"(aH[i]), "v"(bH[j]));
                    asm("v_mfma_f32_16x16x32_bf16 %0, %1, %2, %0"
                        : "+v"(acc[i][j]) : "v"(aL[i]), "v"(bH[j]));
                    asm("v_mfma_f32_16x16x32_bf16 %0, %1, %2, %0"
                        : "+v"(acc[i][j]) : "v"(aH[i]), "v"(bL[j]));
                }
            __builtin_amdgcn_s_setprio(0);
            __builtin_amdgcn_s_barrier();
            __builtin_amdgcn_sched_barrier(0);

            // ---- P1: (iq0, jh1); issue next uA1+uB1 ----
            if (hasNext) { STG_A(nb, 1, kn); STG_B(nb, 1, m0gn, kn); }
#pragma unroll
            for (int j = 0; j < 2; j++) {
                bH[j] = *(const bf16x8*)&sB[cur][0][rB + (2 + j) * 512];
                bL[j] = *(const bf16x8*)&sB[cur][1][rB + (2 + j) * 512];
            }
            __builtin_amdgcn_s_setprio(1);
#pragma unroll
            for (int i = 0; i < 4; i++)
#pragma unroll
                for (int j = 0; j < 2; j++) {
                    asm("v_mfma_f32_16x16x32_bf16 %0, %1, %2, %0"
                        : "+v"(acc[i][2 + j]) : "v"(aH[i]), "v"(bH[j]));
                    asm("v_mfma_f32_16x16x32_bf16 %0, %1, %2, %0"
                        : "+v"(acc[i][2 + j]) : "v"(aL[i]), "v"(bH[j]));
                    asm("v_mfma_f32_16x16x32_bf16 %0, %1, %2, %0"
                        : "+v"(acc[i][2 + j]) : "v"(aH[i]), "v"(bL[j]));
                }
            __builtin_amdgcn_s_setprio(0);
            __builtin_amdgcn_s_barrier();
            __builtin_amdgcn_sched_barrier(0);

            // ---- P2: (iq1, jh1); reuse bH/bL ----
#pragma unroll
            for (int i = 0; i < 4; i++) {
                aH[i] = *(const bf16x8*)&sA[cur][0][rA + 2048 + i * 512];
                aL[i] = *(const bf16x8*)&sA[cur][1][rA + 2048 + i * 512];
            }
            __builtin_amdgcn_s_setprio(1);
#pragma unroll
            for (int i = 0; i < 4; i++)
#pragma unroll
                for (int j = 0; j < 2; j++) {
                    asm("v_mfma_f32_16x16x32_bf16 %0, %1, %2, %0"
                        : "+v"(acc[4 + i][2 + j]) : "v"(aH[i]), "v"(bH[j]));
                    asm("v_mfma_f32_16x16x32_bf16 %0, %1, %2, %0"
                        : "+v"(acc[4 + i][2 + j]) : "v"(aL[i]), "v"(bH[j]));
                    asm("v_mfma_f32_16x16x32_bf16 %0, %1, %2, %0"
                        : "+v"(acc[4 + i][2 + j]) : "v"(aH[i]), "v"(bL[j]));
                }
            __builtin_amdgcn_s_setprio(0);
            __builtin_amdgcn_s_barrier();
            __builtin_amdgcn_sched_barrier(0);

            // ---- P3: (iq1, jh0); drain + flip ----
#pragma unroll
            for (int j = 0; j < 2; j++) {
                bH[j] = *(const bf16x8*)&sB[cur][0][rB + j * 512];
                bL[j] = *(const bf16x8*)&sB[cur][1][rB + j * 512];
            }
            __builtin_amdgcn_s_setprio(1);
#pragma unroll
            for (int i = 0; i < 4; i++)
#pragma unroll
                for (int j = 0; j < 2; j++) {
                    asm("v_mfma_f32_16x16x32_bf16 %0, %1, %2, %0"
                        : "+v"(acc[4 + i][j]) : "v"(aH[i]), "v"(bH[j]));
                    asm("v_mfma_f32_16x16x32_bf16 %0, %1, %2, %0"
                        : "+v"(acc[4 + i][j]) : "v"(aL[i]), "v"(bH[j]));
                    asm("v_mfma_f32_16x16x32_bf16 %0, %1, %2, %0"
                        : "+v"(acc[4 + i][j]) : "v"(aH[i]), "v"(bL[j]));
                }
            __builtin_amdgcn_s_setprio(0);
            asm volatile("s_waitcnt vmcnt(0)" ::: "memory");
            __builtin_amdgcn_s_barrier();
            __builtin_amdgcn_sched_barrier(0);
            cur ^= 1;
        }

        // fold this m-tile into LDS running (max, argmax). j ascending +
        // strict > preserves first-occurrence ties; m-tiles ascend with q.
#pragma unroll
        for (int i = 0; i < 8; i++)
#pragma unroll
            for (int r = 0; r < 4; r++) {
                float m = acc[i][0][r];
                int  id = m0 + wx * 64 + fr;
#pragma unroll
                for (int j = 1; j < 4; j++) {
                    float v = acc[i][j][r];
                    if (v > m) { m = v; id = m0 + wx * 64 + j * 16 + fr; }
                }
#pragma unroll
                for (int off = 1; off < 16; off <<= 1) {
                    float om = __shfl_xor(m, off);
                    int   oi = __shfl_xor(id, off);
                    if (om > m || (om == m && oi < id)) { m = om; id = oi; }
                }
                if (fr == 0) {
                    int rw = wy * 128 + i * 16 + fs * 4 + r;
                    if (m > redm[wx][rw]) { redm[wx][rw] = m; redi[wx][rw] = id; }
                }
            }
    }

    __syncthreads();
    if (t < 256) {
        float bm = redm[0][t]; int bi2 = redi[0][t];
#pragma unroll
        for (int s = 1; s < 4; s++) {   // ascending wx = ascending col
            float p2 = redm[s][t]; int q2 = redi[s][t];
            if (p2 > bm || (p2 == bm && q2 < bi2)) { bm = p2; bi2 = q2; }
        }
        pmax[(b * 2 + ms) * NN + n0 + t] = bm;
        pidx[(b * 2 + ms) * NN + n0 + t] = bi2;
    }
#undef STG
#undef STG_A
#undef STG_B
}

// --- Kernel 3: fused merge (2 m-split partials + sigmoid) + gather/blend ---
__global__ __launch_bounds__(256) void blend_kernel(
        const float* __restrict__ qi, const float* __restrict__ qv,
        const float* __restrict__ ci, const float* __restrict__ cv,
        const float* __restrict__ pmax, const int* __restrict__ pidx,
        const float* __restrict__ st,
        float* __restrict__ out_map,
        float* __restrict__ out_ri, float* __restrict__ out_rv) {
    const int gw   = blockIdx.x * 4 + (threadIdx.x >> 6);   // [0, 8192)
    const int lane = threadIdx.x & 63;

    float pm[2]; int pi[2];
    {
        int b = gw >> 11, n = gw & 2047;
#pragma unroll
        for (int s = 0; s < 2; s++) {
            pm[s] = pmax[(b * 2 + s) * NN + n];
            pi[s] = pidx[(b * 2 + s) * NN + n];
        }
    }

#pragma unroll
    for (int i = 0; i < 4; i++) {
        const int row = gw + i * 8192;
        const int b = row >> 11, n = row & 2047;

        float best = pm[0]; int bi = pi[0];
        if (pm[1] > best || (pm[1] == best && pi[1] < bi)) { best = pm[1]; bi = pi[1]; }
        float thr = 1.0f / (1.0f + expf(-st[n]));
        float rm  = 1.0f / (1.0f + expf(-40.0f * (best - thr)));

        if (i < 3) {   // prefetch next row's merge inputs
            int rown = gw + (i + 1) * 8192;
            int bn_ = rown >> 11, nn_ = rown & 2047;
#pragma unroll
            for (int s = 0; s < 2; s++) {
                pm[s] = pmax[(bn_ * 2 + s) * NN + nn_];
                pi[s] = pidx[(bn_ * 2 + s) * NN + nn_];
            }
        }

        if (lane == 0) out_map[row] = rm;
        const float om = 1.0f - rm;
        const float4* q4 = (const float4*)(qi + (size_t)row * DD);
        const float4* v4 = (const float4*)(qv + (size_t)row * DD);
        const float4* s4 = (const float4*)(ci + ((size_t)b * NN + bi) * DD);
        const float4* w4 = (const float4*)(cv + ((size_t)b * NN + bi) * DD);
        float4* ori = (float4*)(out_ri + (size_t)row * DD);
        float4* orv = (float4*)(out_rv + (size_t)row * DD);
#pragma unroll
        for (int k = 0; k < 3; k++) {
            int f = lane + 64 * k;
            float4 a = q4[f], si = s4[f];
            float4 o;
            o.x = om * a.x + rm * si.x;
            o.y = om * a.y + rm * si.y;
            o.z = om * a.z + rm * si.z;
            o.w = om * a.w + rm * si.w;
            ori[f] = o;
            float4 av = v4[f], sv = w4[f];
            float4 p;
            p.x = om * av.x + rm * sv.x;
            p.y = om * av.y + rm * sv.y;
            p.z = om * av.z + rm * sv.z;
            p.w = om * av.w + rm * sv.w;
            orv[f] = p;
        }
    }
}

extern "C" void kernel_launch(void* const* d_in, const int* in_sizes, int n_in,
                              void* d_out, int out_size, void* d_ws, size_t ws_size,
                              hipStream_t stream) {
    const float* qi = (const float*)d_in[0];
    const float* qv = (const float*)d_in[1];
    const float* ci = (const float*)d_in[2];
    const float* cv = (const float*)d_in[3];
    const float* st = (const float*)d_in[4];

    float* ws    = (float*)d_ws;
    float* pmax  = ws;
    int*   pidx  = (int*)(ws + 65536);

    float* out     = (float*)d_out;
    float* out_map = out;                                  // [B,N]
    float* out_ri  = out + 32768;                          // [B,N,D]
    float* out_rv  = out + 32768 + (size_t)BN * DD;        // [B,N,D]

    // bf16 hi/lo scratch aliases the (not-yet-written) big outputs
    ushort* qh = (ushort*)out_ri;
    ushort* ql = qh + (size_t)BN * DD;
    ushort* ch = (ushort*)out_rv;
    ushort* cl = ch + (size_t)BN * DD;

    normconv_kernel<<<2048, 256, 0, stream>>>(qi, ci, qh, ql, ch, cl);
    dim3 g2(8, 2, BB);
    simmax_kernel<<<g2, 512, 0, stream>>>(qh, ql, ch, cl, pmax, pidx);
    blend_kernel<<<2048, 256, 0, stream>>>(qi, qv, ci, cv, pmax, pidx, st,
                                           out_map, out_ri, out_rv);
}